// Round 8
// baseline (13342.758 us; speedup 1.0000x reference)
//
#include <hip/hip_runtime.h>
#include <math.h>

#define D   512
#define BI  64
#define RR  36
#define BC  64
#define WW  40

// ---------------------------------------------------------------- row stats
__global__ __launch_bounds__(256) void row_stats_k(
    const float* __restrict__ X, const int* __restrict__ lens,
    int rpb, float2* __restrict__ out)
{
  int row = blockIdx.x;
  int b = row / rpb;
  int pos = row - b * rpb;
  bool valid = pos < lens[b];
  int tid = threadIdx.x;
  float s = 0.f, s2 = 0.f;
  if (valid) {
    float2 v = *(const float2*)(X + (size_t)row * D + tid * 2);
    s = v.x + v.y;
    s2 = v.x * v.x + v.y * v.y;
  }
  #pragma unroll
  for (int off = 32; off; off >>= 1) {
    s  += __shfl_down(s, off);
    s2 += __shfl_down(s2, off);
  }
  __shared__ float red[4][2];
  int wid = tid >> 6, lane = tid & 63;
  if (!lane) { red[wid][0] = s; red[wid][1] = s2; }
  __syncthreads();
  if (!tid) {
    s  = red[0][0] + red[1][0] + red[2][0] + red[3][0];
    s2 = red[0][1] + red[1][1] + red[2][1] + red[3][1];
    float mu  = s * (1.f / D);
    float var = s2 * (1.f / D) - mu * mu;
    out[row] = make_float2(mu, 1.f / sqrtf(fmaxf(var, 0.f) + 1e-5f));
  }
}

// ------------------------------------------------- pack Wo -> k-major float4
// Wo4[kb][n] (float4) = { Wo[n][4kb+0..3] },  kb in [0,128), n in [0,512)
__global__ __launch_bounds__(256) void pack_wo_k(
    const float4* __restrict__ Wo, float4* __restrict__ Wo4)
{
  int idx = blockIdx.x * 256 + threadIdx.x;   // 0..65535
  int kb = idx >> 9, n = idx & 511;
  Wo4[idx] = Wo[n * 128 + kb];
}

// ---------------------------------------------------------------- GEMM body
struct GemmP {
  const float* A; const float* Bm; float* C;
  int M, N, ldc; float alpha;
  const float* bias;
  const float2* stats; const float* g; const float* b;
  const int* lens; int rpb;
};

__device__ __forceinline__ void gemm_body(GemmP p, int bx, int by)
{
  __shared__ float As[16][132];
  __shared__ float Bs[16][132];
  int m0 = by * 128, n0 = bx * 128;
  int tid = threadIdx.x;
  int tm = tid & 15, tn = tid >> 4;
  float acc[8][8] = {{0.f}};
  for (int k0 = 0; k0 < D; k0 += 16) {
    #pragma unroll
    for (int l = 0; l < 2; ++l) {
      int fi  = tid + l * 256;        // 0..511
      int row = fi >> 2;              // 0..127
      int kq  = (fi & 3) << 2;        // 0,4,8,12
      {
        int gm = m0 + row;
        float4 x = *(const float4*)(p.A + (size_t)gm * D + k0 + kq);
        if (p.stats) {
          int bb = gm / p.rpb;
          bool val = (gm - bb * p.rpb) < p.lens[bb];
          float2 st = p.stats[gm];
          float4 gg  = *(const float4*)(p.g + k0 + kq);
          float4 bbv = *(const float4*)(p.b + k0 + kq);
          x.x = ((val ? x.x : 0.f) - st.x) * st.y * gg.x + bbv.x;
          x.y = ((val ? x.y : 0.f) - st.x) * st.y * gg.y + bbv.y;
          x.z = ((val ? x.z : 0.f) - st.x) * st.y * gg.z + bbv.z;
          x.w = ((val ? x.w : 0.f) - st.x) * st.y * gg.w + bbv.w;
        }
        As[kq + 0][row] = x.x; As[kq + 1][row] = x.y;
        As[kq + 2][row] = x.z; As[kq + 3][row] = x.w;
      }
      {
        float4 y = *(const float4*)(p.Bm + (size_t)(n0 + row) * D + k0 + kq);
        Bs[kq + 0][row] = y.x; Bs[kq + 1][row] = y.y;
        Bs[kq + 2][row] = y.z; Bs[kq + 3][row] = y.w;
      }
    }
    __syncthreads();
    #pragma unroll
    for (int kk = 0; kk < 16; ++kk) {
      float a[8], bb[8];
      *(float4*)(a)      = *(const float4*)&As[kk][tm * 8];
      *(float4*)(a + 4)  = *(const float4*)&As[kk][tm * 8 + 4];
      *(float4*)(bb)     = *(const float4*)&Bs[kk][tn * 8];
      *(float4*)(bb + 4) = *(const float4*)&Bs[kk][tn * 8 + 4];
      #pragma unroll
      for (int ii = 0; ii < 8; ++ii)
        #pragma unroll
        for (int jj = 0; jj < 8; ++jj)
          acc[ii][jj] = fmaf(a[ii], bb[jj], acc[ii][jj]);
    }
    __syncthreads();
  }
  #pragma unroll
  for (int ii = 0; ii < 8; ++ii) {
    int gm = m0 + tm * 8 + ii;
    #pragma unroll
    for (int jj = 0; jj < 8; jj += 4) {
      int gn = n0 + tn * 8 + jj;
      float4 o;
      o.x = acc[ii][jj+0] * p.alpha + (p.bias ? p.bias[gn+0] : 0.f);
      o.y = acc[ii][jj+1] * p.alpha + (p.bias ? p.bias[gn+1] : 0.f);
      o.z = acc[ii][jj+2] * p.alpha + (p.bias ? p.bias[gn+2] : 0.f);
      o.w = acc[ii][jj+3] * p.alpha + (p.bias ? p.bias[gn+3] : 0.f);
      *(float4*)(p.C + (size_t)gm * p.ldc + gn) = o;
    }
  }
}

// q/k/v projections: grid.z selects which projection.
__global__ __launch_bounds__(256) void qkv_gemm_k(
    const float* imgs, const float* caps,
    const float2* stats_img, const float2* stats_cap,
    const int* img_lens, const int* cap_lens,
    const float* Wq, const float* bq, const float* Wk, const float* bk,
    const float* Wv, const float* bv,
    const float* g1, const float* b1, const float* g2, const float* b2,
    const float* g3, const float* b3,
    float* qo, float* ko, float* vo)
{
  GemmP p;
  p.N = D; p.ldc = D; p.alpha = 1.f;
  int z = blockIdx.z;
  if (z == 0) {
    p.A = caps; p.stats = stats_cap; p.g = g1; p.b = b1;
    p.lens = cap_lens; p.rpb = WW;
    p.Bm = Wq; p.bias = bq; p.C = qo; p.M = BC * WW;
  } else if (z == 1) {
    p.A = imgs; p.stats = stats_img; p.g = g2; p.b = b2;
    p.lens = img_lens; p.rpb = RR;
    p.Bm = Wk; p.bias = bk; p.C = ko; p.M = BI * RR;
  } else {
    p.A = imgs; p.stats = stats_img; p.g = g3; p.b = b3;
    p.lens = img_lens; p.rpb = RR;
    p.Bm = Wv; p.bias = bv; p.C = vo; p.M = BI * RR;
  }
  if (blockIdx.y * 128 >= p.M) return;
  gemm_body(p, blockIdx.x, blockIdx.y);
}

// sims GEMM: S[cw][ir] = (1/sqrt(512)) * q[cw] . k[ir]
__global__ __launch_bounds__(256) void s_gemm_k(
    const float* q, const float* k, float* S)
{
  GemmP p;
  p.A = q; p.Bm = k; p.C = S;
  p.M = BC * WW; p.N = BI * RR; p.ldc = BI * RR;
  p.alpha = 0.04419417382415922f;   // 1/sqrt(512)
  p.bias = nullptr; p.stats = nullptr; p.g = nullptr; p.b = nullptr;
  p.lens = nullptr; p.rpb = 1;
  gemm_body(p, blockIdx.x, blockIdx.y);
}

// ------------------------------------------------------- masked row softmax
__global__ __launch_bounds__(256) void softmax36_k(
    float* __restrict__ S, const int* __restrict__ img_lens)
{
  int row = blockIdx.x * 256 + threadIdx.x;    // 0..163839 = (c*W+w)*64 + i
  int cw = row >> 6, i = row & 63;
  float* p = S + (size_t)cw * (BI * RR) + i * RR;
  int len = img_lens[i];
  float sv[RR];
  float m = -1e30f;
  #pragma unroll
  for (int r = 0; r < RR; ++r) {
    sv[r] = p[r];
    if (r < len && sv[r] > m) m = sv[r];
  }
  float sum = 0.f;
  #pragma unroll
  for (int r = 0; r < RR; ++r) {
    float e = (r < len) ? __expf(sv[r] - m) : 0.f;
    sv[r] = e; sum += e;
  }
  float inv = 1.f / sum;
  #pragma unroll
  for (int r = 0; r < RR; ++r) p[r] = sv[r] * inv;
}

// ------------------- fused: ctx = attn@v, LN, out = y@Wo^T+bo, cosine score
//
// R6 post-mortem: the oa[10][4]/ca[10][4] accumulator ARRAYS were allocated
// to scratch (rule #20: runtime-indexed local arrays -> local memory when
// the compiler declines the big unroll). 19.5 GB WRITE_SIZE == 16*8*10*16B
// per thread of oa scratch stores. Fix: macro-expanded NAMED float4
// accumulators (oa0..oa9 / ca0..ca9) — static component access, guaranteed
// VGPR allocation, independent of unroll heuristics.
#define FOR_JW(X) X(0) X(1) X(2) X(3) X(4) X(5) X(6) X(7) X(8) X(9)

__global__ __launch_bounds__(512, 2) void fused_k(
    const float* __restrict__ q, const float* __restrict__ v,
    const float* __restrict__ attn, const float4* __restrict__ Wo4,
    const float* __restrict__ bo, const float* __restrict__ g4,
    const float* __restrict__ b4, const int* __restrict__ cap_lens,
    float* __restrict__ out)
{
  __shared__ float sm[(WW + RR) * D + WW * RR];   // 40352 f32 = 161408 B
  float* ybuf = sm;                     // 40*512 f32 (ctx -> y)
  float* vbuf = sm + WW * D;            // 36*512 f32 (v -> Wo slab)
  float* att  = sm + (WW + RR) * D;     // 1440 f32 (attn -> red/red2)
  const int i = blockIdx.x, c = blockIdx.y;
  const int tid = threadIdx.x;
  const int nb = tid & 127, wg = tid >> 7;
  const int lane = tid & 63;

  // ---- stage v_i and attn rows
  {
    const float4* vg = (const float4*)(v + (size_t)i * RR * D);
    float4* vb = (float4*)vbuf;
    for (int idx = tid; idx < RR * (D / 4); idx += 512) vb[idx] = vg[idx];
  }
  for (int idx = tid; idx < WW * RR; idx += 512) {
    int w = idx / RR;
    int r = idx - w * RR;
    att[idx] = attn[(size_t)(c * WW + w) * (BI * RR) + i * RR + r];
  }
  __syncthreads();

  // ---- ctx = attn @ v  -> ybuf   (thread: 10 w-rows x 4 consecutive d)
  {
    const int d4 = nb * 4;
#define CA_DECL(J) float4 ca##J = make_float4(0.f, 0.f, 0.f, 0.f);
    FOR_JW(CA_DECL)
#undef CA_DECL
    for (int r = 0; r < RR; ++r) {
      float4 v4 = *(const float4*)&vbuf[r * D + d4];
#define CA_STEP(J) { float a = att[(wg * 10 + (J)) * RR + r];              \
      ca##J.x = fmaf(a, v4.x, ca##J.x); ca##J.y = fmaf(a, v4.y, ca##J.y);  \
      ca##J.z = fmaf(a, v4.z, ca##J.z); ca##J.w = fmaf(a, v4.w, ca##J.w); }
      FOR_JW(CA_STEP)
#undef CA_STEP
    }
#define CA_STORE(J) *(float4*)&ybuf[(wg * 10 + (J)) * D + d4] = ca##J;
    FOR_JW(CA_STORE)
#undef CA_STORE
  }
  __syncthreads();

  // ---- LN stats per ctx row (8 waves x 5 rows)
  float* red = att;   // [40][2] : mu, rsigma
  {
    int wid = tid >> 6;
    for (int w = wid; w < WW; w += 8) {
      float s = 0.f, s2 = 0.f;
      #pragma unroll
      for (int dd = 0; dd < D; dd += 64) {
        float x = ybuf[w * D + dd + lane];
        s += x; s2 += x * x;
      }
      #pragma unroll
      for (int off = 32; off; off >>= 1) {
        s  += __shfl_down(s, off);
        s2 += __shfl_down(s2, off);
      }
      if (!lane) {
        float mu  = s * (1.f / D);
        float var = s2 * (1.f / D) - mu * mu;
        red[w * 2]     = mu;
        red[w * 2 + 1] = 1.f / sqrtf(fmaxf(var, 0.f) + 1e-5f);
      }
    }
  }
  __syncthreads();

  // ---- apply LN in place (thread tid owns column d = tid)
  {
    float gg = g4[tid], bb = b4[tid];
    #pragma unroll
    for (int w = 0; w < WW; ++w) {
      float mu = red[w * 2], rs = red[w * 2 + 1];
      float x = ybuf[w * D + tid];
      ybuf[w * D + tid] = (x - mu) * rs * gg + bb;
    }
  }

  // ---- out = y @ Wo^T + bo, fused with num/den accumulation
  // thread owns columns n_j = nb + 128*j (j=0..3) for its 10 w-rows
  const float bo0 = bo[nb], bo1 = bo[nb + 128], bo2 = bo[nb + 256],
              bo3 = bo[nb + 384];
#define OA_DECL(J) float4 oa##J = make_float4(bo0, bo1, bo2, bo3);
  FOR_JW(OA_DECL)
#undef OA_DECL
  float4* slab = (float4*)vbuf;   // [8][512] float4 Wo chunk
  for (int ch = 0; ch < 16; ++ch) {
    __syncthreads();              // previous chunk fully consumed
    #pragma unroll
    for (int l = 0; l < 8; ++l) {
      int fi = tid + l * 512;     // 0..4095 — linear copy
      slab[fi] = Wo4[ch * 4096 + fi];
    }
    __syncthreads();
    #pragma unroll
    for (int kbl = 0; kbl < 8; ++kbl) {
      float4 wo0 = slab[kbl * 512 + nb];
      float4 wo1 = slab[kbl * 512 + nb + 128];
      float4 wo2 = slab[kbl * 512 + nb + 256];
      float4 wo3 = slab[kbl * 512 + nb + 384];
      int kk = (ch * 8 + kbl) * 4;
#define OA_STEP(J) {                                                        \
      float4 y4 = *(const float4*)&ybuf[(wg * 10 + (J)) * D + kk];          \
      oa##J.x += y4.x*wo0.x + y4.y*wo0.y + y4.z*wo0.z + y4.w*wo0.w;         \
      oa##J.y += y4.x*wo1.x + y4.y*wo1.y + y4.z*wo1.z + y4.w*wo1.w;         \
      oa##J.z += y4.x*wo2.x + y4.y*wo2.y + y4.z*wo2.z + y4.w*wo2.w;         \
      oa##J.w += y4.x*wo3.x + y4.y*wo3.y + y4.z*wo3.z + y4.w*wo3.w; }
      FOR_JW(OA_STEP)
#undef OA_STEP
    }
  }

  // ---- score: num = out.q, den = ||out||; reduce over n per w
  float* red2 = att + 80;   // [40][2 halves][2]
  const float* qbase = q + (size_t)c * WW * D;
  int h = (tid >> 6) & 1;
#define SC_STEP(J) {                                                        \
    int w = wg * 10 + (J);                                                  \
    const float* qrow = qbase + (size_t)w * D + nb;                         \
    float q0 = qrow[0], q1 = qrow[128], q2 = qrow[256], q3 = qrow[384];     \
    float np = oa##J.x*q0 + oa##J.y*q1 + oa##J.z*q2 + oa##J.w*q3;           \
    float dp = oa##J.x*oa##J.x + oa##J.y*oa##J.y + oa##J.z*oa##J.z          \
             + oa##J.w*oa##J.w;                                             \
    _Pragma("unroll")                                                       \
    for (int off = 32; off; off >>= 1) {                                    \
      np += __shfl_down(np, off);                                           \
      dp += __shfl_down(dp, off);                                           \
    }                                                                       \
    if (!lane) {                                                            \
      red2[(w * 2 + h) * 2]     = np;                                       \
      red2[(w * 2 + h) * 2 + 1] = dp;                                       \
    } }
  FOR_JW(SC_STEP)
#undef SC_STEP
  __syncthreads();
  if (tid < WW) {
    float num = red2[(tid * 2) * 2]     + red2[(tid * 2 + 1) * 2];
    float den = red2[(tid * 2) * 2 + 1] + red2[(tid * 2 + 1) * 2 + 1];
    float s = num / (sqrtf(den) + 1e-8f);
    out[((size_t)i * BC + c) * WW + tid] = (tid < cap_lens[c]) ? s : -1.0f;
  }
}

// ---------------------------------------------------------------------------
extern "C" void kernel_launch(void* const* d_in, const int* in_sizes, int n_in,
                              void* d_out, int out_size, void* d_ws, size_t ws_size,
                              hipStream_t stream)
{
  const float* imgs     = (const float*)d_in[0];
  const float* caps     = (const float*)d_in[1];
  const int*   img_lens = (const int*)d_in[2];
  const int*   cap_lens = (const int*)d_in[3];
  const float* Wq = (const float*)d_in[4];
  const float* bq = (const float*)d_in[5];
  const float* Wk = (const float*)d_in[6];
  const float* bk = (const float*)d_in[7];
  const float* Wv = (const float*)d_in[8];
  const float* bv = (const float*)d_in[9];
  const float* Wo = (const float*)d_in[10];
  const float* bo = (const float*)d_in[11];
  const float* g1 = (const float*)d_in[12];
  const float* b1 = (const float*)d_in[13];
  const float* g2 = (const float*)d_in[14];
  const float* b2 = (const float*)d_in[15];
  const float* g3 = (const float*)d_in[16];
  const float* b3 = (const float*)d_in[17];
  const float* g4 = (const float*)d_in[18];
  const float* b4 = (const float*)d_in[19];
  float* out = (float*)d_out;

  // Workspace layout (floats):
  //   stats_cap 2*2560 | stats_img 2*2304 | qb 2560*512 | kb 2304*512
  //   vb 2304*512 | Sb 2560*2304 | Wo4 512*512
  const size_t WS_FLOATS =
      (size_t)2 * (BC * WW) + 2 * (BI * RR) +
      (size_t)BC * WW * D + 2 * (size_t)BI * RR * D +
      (size_t)BC * WW * BI * RR + (size_t)D * D;
  if (ws_size < WS_FLOATS * sizeof(float)) return;  // guard: fault-free diag

  float*  ws        = (float*)d_ws;
  float2* stats_cap = (float2*)ws;                         // 2560
  float2* stats_img = stats_cap + BC * WW;                 // 2304
  float*  qb  = (float*)(stats_img + BI * RR);             // 2560*512
  float*  kb  = qb + (size_t)BC * WW * D;                  // 2304*512
  float*  vb  = kb + (size_t)BI * RR * D;                  // 2304*512
  float*  Sb  = vb + (size_t)BI * RR * D;                  // 2560*2304
  float*  Wo4 = Sb + (size_t)BC * WW * BI * RR;            // 512*512

  row_stats_k<<<BC * WW, 256, 0, stream>>>(caps, cap_lens, WW, stats_cap);
  row_stats_k<<<BI * RR, 256, 0, stream>>>(imgs, img_lens, RR, stats_img);
  pack_wo_k<<<(D * (D / 4)) / 256, 256, 0, stream>>>((const float4*)Wo, (float4*)Wo4);

  qkv_gemm_k<<<dim3(4, 20, 3), 256, 0, stream>>>(
      imgs, caps, stats_img, stats_cap, img_lens, cap_lens,
      Wq, bq, Wk, bk, Wv, bv, g1, b1, g2, b2, g3, b3, qb, kb, vb);

  s_gemm_k<<<dim3(18, 20), 256, 0, stream>>>(qb, kb, Sb);

  softmax36_k<<<640, 256, 0, stream>>>(Sb, img_lens);

  fused_k<<<dim3(BI, BC), 512, 0, stream>>>(
      qb, vb, Sb, (const float4*)Wo4, bo, g4, b4, cap_lens, out);
}

// Round 10
// 8935.359 us; speedup vs baseline: 1.4933x; 1.4933x over previous
//
#include <hip/hip_runtime.h>
#include <math.h>

#define D   512
#define BI  64
#define RR  36
#define BC  64
#define WW  40

// ---------------------------------------------------------------- row stats
__global__ __launch_bounds__(256) void row_stats_k(
    const float* __restrict__ X, const int* __restrict__ lens,
    int rpb, float2* __restrict__ out)
{
  int row = blockIdx.x;
  int b = row / rpb;
  int pos = row - b * rpb;
  bool valid = pos < lens[b];
  int tid = threadIdx.x;
  float s = 0.f, s2 = 0.f;
  if (valid) {
    float2 v = *(const float2*)(X + (size_t)row * D + tid * 2);
    s = v.x + v.y;
    s2 = v.x * v.x + v.y * v.y;
  }
  #pragma unroll
  for (int off = 32; off; off >>= 1) {
    s  += __shfl_down(s, off);
    s2 += __shfl_down(s2, off);
  }
  __shared__ float red[4][2];
  int wid = tid >> 6, lane = tid & 63;
  if (!lane) { red[wid][0] = s; red[wid][1] = s2; }
  __syncthreads();
  if (!tid) {
    s  = red[0][0] + red[1][0] + red[2][0] + red[3][0];
    s2 = red[0][1] + red[1][1] + red[2][1] + red[3][1];
    float mu  = s * (1.f / D);
    float var = s2 * (1.f / D) - mu * mu;
    out[row] = make_float2(mu, 1.f / sqrtf(fmaxf(var, 0.f) + 1e-5f));
  }
}

// ------------------------------------------------- pack Wo -> k-major float4
// Wo4[kb][n] (float4) = { Wo[n][4kb+0..3] },  kb in [0,128), n in [0,512)
__global__ __launch_bounds__(256) void pack_wo_k(
    const float4* __restrict__ Wo, float4* __restrict__ Wo4)
{
  int idx = blockIdx.x * 256 + threadIdx.x;   // 0..65535
  int kb = idx >> 9, n = idx & 511;
  Wo4[idx] = Wo[n * 128 + kb];
}

// ---------------------------------------------------------------- GEMM body
struct GemmP {
  const float* A; const float* Bm; float* C;
  int M, N, ldc; float alpha;
  const float* bias;
  const float2* stats; const float* g; const float* b;
  const int* lens; int rpb;
};

__device__ __forceinline__ void gemm_body(GemmP p, int bx, int by)
{
  __shared__ float As[16][132];
  __shared__ float Bs[16][132];
  int m0 = by * 128, n0 = bx * 128;
  int tid = threadIdx.x;
  int tm = tid & 15, tn = tid >> 4;
  float acc[8][8] = {{0.f}};
  for (int k0 = 0; k0 < D; k0 += 16) {
    #pragma unroll
    for (int l = 0; l < 2; ++l) {
      int fi  = tid + l * 256;        // 0..511
      int row = fi >> 2;              // 0..127
      int kq  = (fi & 3) << 2;        // 0,4,8,12
      {
        int gm = m0 + row;
        float4 x = *(const float4*)(p.A + (size_t)gm * D + k0 + kq);
        if (p.stats) {
          int bb = gm / p.rpb;
          bool val = (gm - bb * p.rpb) < p.lens[bb];
          float2 st = p.stats[gm];
          float4 gg  = *(const float4*)(p.g + k0 + kq);
          float4 bbv = *(const float4*)(p.b + k0 + kq);
          x.x = ((val ? x.x : 0.f) - st.x) * st.y * gg.x + bbv.x;
          x.y = ((val ? x.y : 0.f) - st.x) * st.y * gg.y + bbv.y;
          x.z = ((val ? x.z : 0.f) - st.x) * st.y * gg.z + bbv.z;
          x.w = ((val ? x.w : 0.f) - st.x) * st.y * gg.w + bbv.w;
        }
        As[kq + 0][row] = x.x; As[kq + 1][row] = x.y;
        As[kq + 2][row] = x.z; As[kq + 3][row] = x.w;
      }
      {
        float4 y = *(const float4*)(p.Bm + (size_t)(n0 + row) * D + k0 + kq);
        Bs[kq + 0][row] = y.x; Bs[kq + 1][row] = y.y;
        Bs[kq + 2][row] = y.z; Bs[kq + 3][row] = y.w;
      }
    }
    __syncthreads();
    #pragma unroll
    for (int kk = 0; kk < 16; ++kk) {
      float a[8], bb[8];
      *(float4*)(a)      = *(const float4*)&As[kk][tm * 8];
      *(float4*)(a + 4)  = *(const float4*)&As[kk][tm * 8 + 4];
      *(float4*)(bb)     = *(const float4*)&Bs[kk][tn * 8];
      *(float4*)(bb + 4) = *(const float4*)&Bs[kk][tn * 8 + 4];
      #pragma unroll
      for (int ii = 0; ii < 8; ++ii)
        #pragma unroll
        for (int jj = 0; jj < 8; ++jj)
          acc[ii][jj] = fmaf(a[ii], bb[jj], acc[ii][jj]);
    }
    __syncthreads();
  }
  #pragma unroll
  for (int ii = 0; ii < 8; ++ii) {
    int gm = m0 + tm * 8 + ii;
    #pragma unroll
    for (int jj = 0; jj < 8; jj += 4) {
      int gn = n0 + tn * 8 + jj;
      float4 o;
      o.x = acc[ii][jj+0] * p.alpha + (p.bias ? p.bias[gn+0] : 0.f);
      o.y = acc[ii][jj+1] * p.alpha + (p.bias ? p.bias[gn+1] : 0.f);
      o.z = acc[ii][jj+2] * p.alpha + (p.bias ? p.bias[gn+2] : 0.f);
      o.w = acc[ii][jj+3] * p.alpha + (p.bias ? p.bias[gn+3] : 0.f);
      *(float4*)(p.C + (size_t)gm * p.ldc + gn) = o;
    }
  }
}

// q/k/v projections: grid.z selects which projection.
__global__ __launch_bounds__(256) void qkv_gemm_k(
    const float* imgs, const float* caps,
    const float2* stats_img, const float2* stats_cap,
    const int* img_lens, const int* cap_lens,
    const float* Wq, const float* bq, const float* Wk, const float* bk,
    const float* Wv, const float* bv,
    const float* g1, const float* b1, const float* g2, const float* b2,
    const float* g3, const float* b3,
    float* qo, float* ko, float* vo)
{
  GemmP p;
  p.N = D; p.ldc = D; p.alpha = 1.f;
  int z = blockIdx.z;
  if (z == 0) {
    p.A = caps; p.stats = stats_cap; p.g = g1; p.b = b1;
    p.lens = cap_lens; p.rpb = WW;
    p.Bm = Wq; p.bias = bq; p.C = qo; p.M = BC * WW;
  } else if (z == 1) {
    p.A = imgs; p.stats = stats_img; p.g = g2; p.b = b2;
    p.lens = img_lens; p.rpb = RR;
    p.Bm = Wk; p.bias = bk; p.C = ko; p.M = BI * RR;
  } else {
    p.A = imgs; p.stats = stats_img; p.g = g3; p.b = b3;
    p.lens = img_lens; p.rpb = RR;
    p.Bm = Wv; p.bias = bv; p.C = vo; p.M = BI * RR;
  }
  if (blockIdx.y * 128 >= p.M) return;
  gemm_body(p, blockIdx.x, blockIdx.y);
}

// sims GEMM: S[cw][ir] = (1/sqrt(512)) * q[cw] . k[ir]
__global__ __launch_bounds__(256) void s_gemm_k(
    const float* q, const float* k, float* S)
{
  GemmP p;
  p.A = q; p.Bm = k; p.C = S;
  p.M = BC * WW; p.N = BI * RR; p.ldc = BI * RR;
  p.alpha = 0.04419417382415922f;   // 1/sqrt(512)
  p.bias = nullptr; p.stats = nullptr; p.g = nullptr; p.b = nullptr;
  p.lens = nullptr; p.rpb = 1;
  gemm_body(p, blockIdx.x, blockIdx.y);
}

// ------------------------------------------------------- masked row softmax
__global__ __launch_bounds__(256) void softmax36_k(
    float* __restrict__ S, const int* __restrict__ img_lens)
{
  int row = blockIdx.x * 256 + threadIdx.x;    // 0..163839 = (c*W+w)*64 + i
  int cw = row >> 6, i = row & 63;
  float* p = S + (size_t)cw * (BI * RR) + i * RR;
  int len = img_lens[i];
  float sv[RR];
  float m = -1e30f;
  #pragma unroll
  for (int r = 0; r < RR; ++r) {
    sv[r] = p[r];
    if (r < len && sv[r] > m) m = sv[r];
  }
  float sum = 0.f;
  #pragma unroll
  for (int r = 0; r < RR; ++r) {
    float e = (r < len) ? __expf(sv[r] - m) : 0.f;
    sv[r] = e; sum += e;
  }
  float inv = 1.f / sum;
  #pragma unroll
  for (int r = 0; r < RR; ++r) p[r] = sv[r] * inv;
}

// ------------------- fused: ctx = attn@v, LN, out = y@Wo^T+bo, cosine score
//
// R8 post-mortem: naming the accumulators didn't stop the spill — VGPR_Count
// pinned at 128 (hipcc won't exceed it here) while the unrolled ch/kbl loop
// demands ~150-200 live values; the named accumulators were the spill
// VICTIMS. Fix: halve per-thread state. 1024 threads, 5 w-rows/thread
// (oa0..oa4 = 20 VGPR + wo0..3 + y4 ~ 60-80 live) => fits 128 with headroom.
// Note: 1024 thr + 158KiB LDS = 1 block/CU = 4 waves/SIMD, which REQUIRES
// <=128 VGPR — this design targets the cap instead of fighting it.
#define FOR_J5(X) X(0) X(1) X(2) X(3) X(4)

__global__ __launch_bounds__(1024) void fused_k(
    const float* __restrict__ q, const float* __restrict__ v,
    const float* __restrict__ attn, const float4* __restrict__ Wo4,
    const float* __restrict__ bo, const float* __restrict__ g4,
    const float* __restrict__ b4, const int* __restrict__ cap_lens,
    float* __restrict__ out)
{
  __shared__ float sm[(WW + RR) * D + WW * RR];   // 40352 f32 = 161408 B
  float* ybuf = sm;                     // 40*512 f32 (ctx -> y)
  float* vbuf = sm + WW * D;            // 36*512 f32 (v -> Wo slab)
  float* att  = sm + (WW + RR) * D;     // 1440 f32 (attn -> red/red2)
  const int i = blockIdx.x, c = blockIdx.y;
  const int tid = threadIdx.x;
  const int nb = tid & 127;             // column block 0..127
  const int wg = tid >> 7;              // row group 0..7 (5 rows each)
  const int lane = tid & 63;

  // ---- stage v_i and attn rows
  {
    const float4* vg = (const float4*)(v + (size_t)i * RR * D);
    float4* vb = (float4*)vbuf;
    for (int idx = tid; idx < RR * (D / 4); idx += 1024) vb[idx] = vg[idx];
  }
  for (int idx = tid; idx < WW * RR; idx += 1024) {
    int w = idx / RR;
    int r = idx - w * RR;
    att[idx] = attn[(size_t)(c * WW + w) * (BI * RR) + i * RR + r];
  }
  __syncthreads();

  // ---- ctx = attn @ v  -> ybuf   (thread: 5 w-rows x 4 consecutive d)
  {
    const int d4 = nb * 4;
#define CA_DECL(J) float4 ca##J = make_float4(0.f, 0.f, 0.f, 0.f);
    FOR_J5(CA_DECL)
#undef CA_DECL
    for (int r = 0; r < RR; ++r) {
      float4 v4 = *(const float4*)&vbuf[r * D + d4];
#define CA_STEP(J) { float a = att[(wg * 5 + (J)) * RR + r];               \
      ca##J.x = fmaf(a, v4.x, ca##J.x); ca##J.y = fmaf(a, v4.y, ca##J.y);  \
      ca##J.z = fmaf(a, v4.z, ca##J.z); ca##J.w = fmaf(a, v4.w, ca##J.w); }
      FOR_J5(CA_STEP)
#undef CA_STEP
    }
#define CA_STORE(J) *(float4*)&ybuf[(wg * 5 + (J)) * D + d4] = ca##J;
    FOR_J5(CA_STORE)
#undef CA_STORE
  }
  __syncthreads();

  // ---- LN stats per ctx row (16 waves cover 40 rows)
  float* red = att;   // [40][2] : mu, rsigma
  {
    int wid = tid >> 6;
    for (int w = wid; w < WW; w += 16) {
      float s = 0.f, s2 = 0.f;
      #pragma unroll
      for (int dd = 0; dd < D; dd += 64) {
        float x = ybuf[w * D + dd + lane];
        s += x; s2 += x * x;
      }
      #pragma unroll
      for (int off = 32; off; off >>= 1) {
        s  += __shfl_down(s, off);
        s2 += __shfl_down(s2, off);
      }
      if (!lane) {
        float mu  = s * (1.f / D);
        float var = s2 * (1.f / D) - mu * mu;
        red[w * 2]     = mu;
        red[w * 2 + 1] = 1.f / sqrtf(fmaxf(var, 0.f) + 1e-5f);
      }
    }
  }
  __syncthreads();

  // ---- apply LN in place (thread owns column col, half the rows)
  {
    int col  = tid & 511;
    int half = tid >> 9;                 // 0 or 1
    float gg = g4[col], bb = b4[col];
    #pragma unroll
    for (int w = half; w < WW; w += 2) {
      float mu = red[w * 2], rs = red[w * 2 + 1];
      float x = ybuf[w * D + col];
      ybuf[w * D + col] = (x - mu) * rs * gg + bb;
    }
  }

  // ---- out = y @ Wo^T + bo, fused with num/den accumulation
  // thread owns columns n_j = nb + 128*j (j=0..3) for its 5 w-rows
  const float bo0 = bo[nb], bo1 = bo[nb + 128], bo2 = bo[nb + 256],
              bo3 = bo[nb + 384];
#define OA_DECL(J) float4 oa##J = make_float4(bo0, bo1, bo2, bo3);
  FOR_J5(OA_DECL)
#undef OA_DECL
  float4* slab = (float4*)vbuf;   // [8][512] float4 Wo chunk
  for (int ch = 0; ch < 16; ++ch) {
    __syncthreads();              // previous chunk fully consumed
    #pragma unroll
    for (int l = 0; l < 4; ++l) {
      int fi = tid + l * 1024;    // 0..4095 — linear copy
      slab[fi] = Wo4[ch * 4096 + fi];
    }
    __syncthreads();
    #pragma unroll
    for (int kbl = 0; kbl < 8; ++kbl) {
      float4 wo0 = slab[kbl * 512 + nb];
      float4 wo1 = slab[kbl * 512 + nb + 128];
      float4 wo2 = slab[kbl * 512 + nb + 256];
      float4 wo3 = slab[kbl * 512 + nb + 384];
      int kk = (ch * 8 + kbl) * 4;
#define OA_STEP(J) {                                                        \
      float4 y4 = *(const float4*)&ybuf[(wg * 5 + (J)) * D + kk];           \
      oa##J.x += y4.x*wo0.x + y4.y*wo0.y + y4.z*wo0.z + y4.w*wo0.w;         \
      oa##J.y += y4.x*wo1.x + y4.y*wo1.y + y4.z*wo1.z + y4.w*wo1.w;         \
      oa##J.z += y4.x*wo2.x + y4.y*wo2.y + y4.z*wo2.z + y4.w*wo2.w;         \
      oa##J.w += y4.x*wo3.x + y4.y*wo3.y + y4.z*wo3.z + y4.w*wo3.w; }
      FOR_J5(OA_STEP)
#undef OA_STEP
    }
  }

  // ---- score: num = out.q, den = ||out||; reduce over n per w
  float* red2 = att + 80;   // [40][2 halves][2]
  const float* qbase = q + (size_t)c * WW * D;
  int h = (tid >> 6) & 1;
#define SC_STEP(J) {                                                        \
    int w = wg * 5 + (J);                                                   \
    const float* qrow = qbase + (size_t)w * D + nb;                         \
    float q0 = qrow[0], q1 = qrow[128], q2 = qrow[256], q3 = qrow[384];     \
    float np = oa##J.x*q0 + oa##J.y*q1 + oa##J.z*q2 + oa##J.w*q3;           \
    float dp = oa##J.x*oa##J.x + oa##J.y*oa##J.y + oa##J.z*oa##J.z          \
             + oa##J.w*oa##J.w;                                             \
    _Pragma("unroll")                                                       \
    for (int off = 32; off; off >>= 1) {                                    \
      np += __shfl_down(np, off);                                           \
      dp += __shfl_down(dp, off);                                           \
    }                                                                       \
    if (!lane) {                                                            \
      red2[(w * 2 + h) * 2]     = np;                                       \
      red2[(w * 2 + h) * 2 + 1] = dp;                                       \
    } }
  FOR_J5(SC_STEP)
#undef SC_STEP
  __syncthreads();
  if (tid < WW) {
    float num = red2[(tid * 2) * 2]     + red2[(tid * 2 + 1) * 2];
    float den = red2[(tid * 2) * 2 + 1] + red2[(tid * 2 + 1) * 2 + 1];
    float s = num / (sqrtf(den) + 1e-8f);
    out[((size_t)i * BC + c) * WW + tid] = (tid < cap_lens[c]) ? s : -1.0f;
  }
}

// ---------------------------------------------------------------------------
extern "C" void kernel_launch(void* const* d_in, const int* in_sizes, int n_in,
                              void* d_out, int out_size, void* d_ws, size_t ws_size,
                              hipStream_t stream)
{
  const float* imgs     = (const float*)d_in[0];
  const float* caps     = (const float*)d_in[1];
  const int*   img_lens = (const int*)d_in[2];
  const int*   cap_lens = (const int*)d_in[3];
  const float* Wq = (const float*)d_in[4];
  const float* bq = (const float*)d_in[5];
  const float* Wk = (const float*)d_in[6];
  const float* bk = (const float*)d_in[7];
  const float* Wv = (const float*)d_in[8];
  const float* bv = (const float*)d_in[9];
  const float* Wo = (const float*)d_in[10];
  const float* bo = (const float*)d_in[11];
  const float* g1 = (const float*)d_in[12];
  const float* b1 = (const float*)d_in[13];
  const float* g2 = (const float*)d_in[14];
  const float* b2 = (const float*)d_in[15];
  const float* g3 = (const float*)d_in[16];
  const float* b3 = (const float*)d_in[17];
  const float* g4 = (const float*)d_in[18];
  const float* b4 = (const float*)d_in[19];
  float* out = (float*)d_out;

  // Workspace layout (floats):
  //   stats_cap 2*2560 | stats_img 2*2304 | qb 2560*512 | kb 2304*512
  //   vb 2304*512 | Sb 2560*2304 | Wo4 512*512
  const size_t WS_FLOATS =
      (size_t)2 * (BC * WW) + 2 * (BI * RR) +
      (size_t)BC * WW * D + 2 * (size_t)BI * RR * D +
      (size_t)BC * WW * BI * RR + (size_t)D * D;
  if (ws_size < WS_FLOATS * sizeof(float)) return;  // guard: fault-free diag

  float*  ws        = (float*)d_ws;
  float2* stats_cap = (float2*)ws;                         // 2560
  float2* stats_img = stats_cap + BC * WW;                 // 2304
  float*  qb  = (float*)(stats_img + BI * RR);             // 2560*512
  float*  kb  = qb + (size_t)BC * WW * D;                  // 2304*512
  float*  vb  = kb + (size_t)BI * RR * D;                  // 2304*512
  float*  Sb  = vb + (size_t)BI * RR * D;                  // 2560*2304
  float*  Wo4 = Sb + (size_t)BC * WW * BI * RR;            // 512*512

  row_stats_k<<<BC * WW, 256, 0, stream>>>(caps, cap_lens, WW, stats_cap);
  row_stats_k<<<BI * RR, 256, 0, stream>>>(imgs, img_lens, RR, stats_img);
  pack_wo_k<<<(D * (D / 4)) / 256, 256, 0, stream>>>((const float4*)Wo, (float4*)Wo4);

  qkv_gemm_k<<<dim3(4, 20, 3), 256, 0, stream>>>(
      imgs, caps, stats_img, stats_cap, img_lens, cap_lens,
      Wq, bq, Wk, bk, Wv, bv, g1, b1, g2, b2, g3, b3, qb, kb, vb);

  s_gemm_k<<<dim3(18, 20), 256, 0, stream>>>(qb, kb, Sb);

  softmax36_k<<<640, 256, 0, stream>>>(Sb, img_lens);

  fused_k<<<dim3(BI, BC), 1024, 0, stream>>>(
      qb, vb, Sb, (const float4*)Wo4, bo, g4, b4, cap_lens, out);
}

// Round 12
// 1863.599 us; speedup vs baseline: 7.1597x; 4.7947x over previous
//
#include <hip/hip_runtime.h>
#include <math.h>

#define D   512
#define BI  64
#define RR  36
#define BC  64
#define WW  40

// ---------------------------------------------------------------- row stats
__global__ __launch_bounds__(256) void row_stats_k(
    const float* __restrict__ X, const int* __restrict__ lens,
    int rpb, float2* __restrict__ out)
{
  int row = blockIdx.x;
  int b = row / rpb;
  int pos = row - b * rpb;
  bool valid = pos < lens[b];
  int tid = threadIdx.x;
  float s = 0.f, s2 = 0.f;
  if (valid) {
    float2 v = *(const float2*)(X + (size_t)row * D + tid * 2);
    s = v.x + v.y;
    s2 = v.x * v.x + v.y * v.y;
  }
  #pragma unroll
  for (int off = 32; off; off >>= 1) {
    s  += __shfl_down(s, off);
    s2 += __shfl_down(s2, off);
  }
  __shared__ float red[4][2];
  int wid = tid >> 6, lane = tid & 63;
  if (!lane) { red[wid][0] = s; red[wid][1] = s2; }
  __syncthreads();
  if (!tid) {
    s  = red[0][0] + red[1][0] + red[2][0] + red[3][0];
    s2 = red[0][1] + red[1][1] + red[2][1] + red[3][1];
    float mu  = s * (1.f / D);
    float var = s2 * (1.f / D) - mu * mu;
    out[row] = make_float2(mu, 1.f / sqrtf(fmaxf(var, 0.f) + 1e-5f));
  }
}

// ------------------------------------------------- pack Wo -> k-major float4
// Wo4[kb][n] (float4) = { Wo[n][4kb+0..3] },  kb in [0,128), n in [0,512)
__global__ __launch_bounds__(256) void pack_wo_k(
    const float4* __restrict__ Wo, float4* __restrict__ Wo4)
{
  int idx = blockIdx.x * 256 + threadIdx.x;   // 0..65535
  int kb = idx >> 9, n = idx & 511;
  Wo4[idx] = Wo[n * 128 + kb];
}

// ---------------------------------------------------------------- GEMM body
struct GemmP {
  const float* A; const float* Bm; float* C;
  int M, N, ldc; float alpha;
  const float* bias;
  const float2* stats; const float* g; const float* b;
  const int* lens; int rpb;
};

__device__ __forceinline__ void gemm_body(GemmP p, int bx, int by)
{
  __shared__ float As[16][132];
  __shared__ float Bs[16][132];
  int m0 = by * 128, n0 = bx * 128;
  int tid = threadIdx.x;
  int tm = tid & 15, tn = tid >> 4;
  float acc[8][8] = {{0.f}};
  for (int k0 = 0; k0 < D; k0 += 16) {
    #pragma unroll
    for (int l = 0; l < 2; ++l) {
      int fi  = tid + l * 256;        // 0..511
      int row = fi >> 2;              // 0..127
      int kq  = (fi & 3) << 2;        // 0,4,8,12
      {
        int gm = m0 + row;
        float4 x = *(const float4*)(p.A + (size_t)gm * D + k0 + kq);
        if (p.stats) {
          int bb = gm / p.rpb;
          bool val = (gm - bb * p.rpb) < p.lens[bb];
          float2 st = p.stats[gm];
          float4 gg  = *(const float4*)(p.g + k0 + kq);
          float4 bbv = *(const float4*)(p.b + k0 + kq);
          x.x = ((val ? x.x : 0.f) - st.x) * st.y * gg.x + bbv.x;
          x.y = ((val ? x.y : 0.f) - st.x) * st.y * gg.y + bbv.y;
          x.z = ((val ? x.z : 0.f) - st.x) * st.y * gg.z + bbv.z;
          x.w = ((val ? x.w : 0.f) - st.x) * st.y * gg.w + bbv.w;
        }
        As[kq + 0][row] = x.x; As[kq + 1][row] = x.y;
        As[kq + 2][row] = x.z; As[kq + 3][row] = x.w;
      }
      {
        float4 y = *(const float4*)(p.Bm + (size_t)(n0 + row) * D + k0 + kq);
        Bs[kq + 0][row] = y.x; Bs[kq + 1][row] = y.y;
        Bs[kq + 2][row] = y.z; Bs[kq + 3][row] = y.w;
      }
    }
    __syncthreads();
    #pragma unroll
    for (int kk = 0; kk < 16; ++kk) {
      float a[8], bb[8];
      *(float4*)(a)      = *(const float4*)&As[kk][tm * 8];
      *(float4*)(a + 4)  = *(const float4*)&As[kk][tm * 8 + 4];
      *(float4*)(bb)     = *(const float4*)&Bs[kk][tn * 8];
      *(float4*)(bb + 4) = *(const float4*)&Bs[kk][tn * 8 + 4];
      #pragma unroll
      for (int ii = 0; ii < 8; ++ii)
        #pragma unroll
        for (int jj = 0; jj < 8; ++jj)
          acc[ii][jj] = fmaf(a[ii], bb[jj], acc[ii][jj]);
    }
    __syncthreads();
  }
  #pragma unroll
  for (int ii = 0; ii < 8; ++ii) {
    int gm = m0 + tm * 8 + ii;
    #pragma unroll
    for (int jj = 0; jj < 8; jj += 4) {
      int gn = n0 + tn * 8 + jj;
      float4 o;
      o.x = acc[ii][jj+0] * p.alpha + (p.bias ? p.bias[gn+0] : 0.f);
      o.y = acc[ii][jj+1] * p.alpha + (p.bias ? p.bias[gn+1] : 0.f);
      o.z = acc[ii][jj+2] * p.alpha + (p.bias ? p.bias[gn+2] : 0.f);
      o.w = acc[ii][jj+3] * p.alpha + (p.bias ? p.bias[gn+3] : 0.f);
      *(float4*)(p.C + (size_t)gm * p.ldc + gn) = o;
    }
  }
}

// q/k/v projections: grid.z selects which projection.
__global__ __launch_bounds__(256) void qkv_gemm_k(
    const float* imgs, const float* caps,
    const float2* stats_img, const float2* stats_cap,
    const int* img_lens, const int* cap_lens,
    const float* Wq, const float* bq, const float* Wk, const float* bk,
    const float* Wv, const float* bv,
    const float* g1, const float* b1, const float* g2, const float* b2,
    const float* g3, const float* b3,
    float* qo, float* ko, float* vo)
{
  GemmP p;
  p.N = D; p.ldc = D; p.alpha = 1.f;
  int z = blockIdx.z;
  if (z == 0) {
    p.A = caps; p.stats = stats_cap; p.g = g1; p.b = b1;
    p.lens = cap_lens; p.rpb = WW;
    p.Bm = Wq; p.bias = bq; p.C = qo; p.M = BC * WW;
  } else if (z == 1) {
    p.A = imgs; p.stats = stats_img; p.g = g2; p.b = b2;
    p.lens = img_lens; p.rpb = RR;
    p.Bm = Wk; p.bias = bk; p.C = ko; p.M = BI * RR;
  } else {
    p.A = imgs; p.stats = stats_img; p.g = g3; p.b = b3;
    p.lens = img_lens; p.rpb = RR;
    p.Bm = Wv; p.bias = bv; p.C = vo; p.M = BI * RR;
  }
  if (blockIdx.y * 128 >= p.M) return;
  gemm_body(p, blockIdx.x, blockIdx.y);
}

// sims GEMM: S[cw][ir] = (1/sqrt(512)) * q[cw] . k[ir]
__global__ __launch_bounds__(256) void s_gemm_k(
    const float* q, const float* k, float* S)
{
  GemmP p;
  p.A = q; p.Bm = k; p.C = S;
  p.M = BC * WW; p.N = BI * RR; p.ldc = BI * RR;
  p.alpha = 0.04419417382415922f;   // 1/sqrt(512)
  p.bias = nullptr; p.stats = nullptr; p.g = nullptr; p.b = nullptr;
  p.lens = nullptr; p.rpb = 1;
  gemm_body(p, blockIdx.x, blockIdx.y);
}

// ------------------------------------------------------- masked row softmax
__global__ __launch_bounds__(256) void softmax36_k(
    float* __restrict__ S, const int* __restrict__ img_lens)
{
  int row = blockIdx.x * 256 + threadIdx.x;    // 0..163839 = (c*W+w)*64 + i
  int cw = row >> 6, i = row & 63;
  float* p = S + (size_t)cw * (BI * RR) + i * RR;
  int len = img_lens[i];
  float sv[RR];
  float m = -1e30f;
  #pragma unroll
  for (int r = 0; r < RR; ++r) {
    sv[r] = p[r];
    if (r < len && sv[r] > m) m = sv[r];
  }
  float sum = 0.f;
  #pragma unroll
  for (int r = 0; r < RR; ++r) {
    float e = (r < len) ? __expf(sv[r] - m) : 0.f;
    sv[r] = e; sum += e;
  }
  float inv = 1.f / sum;
  #pragma unroll
  for (int r = 0; r < RR; ++r) p[r] = sv[r] * inv;
}

// ------------------- fused: ctx = attn@v, LN, out = y@Wo^T+bo, cosine score
//
// R10 post-mortem: hipcc's occupancy heuristic picks VGPR_Count =
// 65536/blocksize (2 blocks/CU worth) in every configuration tried
// (512->128, 1024->64), ignoring that 158KiB LDS caps us at 1 block/CU,
// then SPILLS to meet its own target (WRITE_SIZE 19-23 GB of scratch).
// __launch_bounds__'s 2nd arg only sets a MINIMUM occupancy (R6: no-op).
// Fix: amdgpu_waves_per_eu(4,4) pins min AND MAX waves/EU at the physical
// residency (16 waves / 4 SIMDs, 1 block/CU) -> VGPR budget 128, where the
// ~85-reg demand fits. kbl loop capped at unroll 2 to bound the scheduler's
// wo-hoisting pressure under the 128 ceiling.
#define FOR_J5(X) X(0) X(1) X(2) X(3) X(4)

__global__ __launch_bounds__(1024)
__attribute__((amdgpu_waves_per_eu(4, 4)))
void fused_k(
    const float* __restrict__ q, const float* __restrict__ v,
    const float* __restrict__ attn, const float4* __restrict__ Wo4,
    const float* __restrict__ bo, const float* __restrict__ g4,
    const float* __restrict__ b4, const int* __restrict__ cap_lens,
    float* __restrict__ out)
{
  __shared__ float sm[(WW + RR) * D + WW * RR];   // 40352 f32 = 161408 B
  float* ybuf = sm;                     // 40*512 f32 (ctx -> y)
  float* vbuf = sm + WW * D;            // 36*512 f32 (v -> Wo slab)
  float* att  = sm + (WW + RR) * D;     // 1440 f32 (attn -> red/red2)
  const int i = blockIdx.x, c = blockIdx.y;
  const int tid = threadIdx.x;
  const int nb = tid & 127;             // column block 0..127
  const int wg = tid >> 7;              // row group 0..7 (5 rows each)
  const int lane = tid & 63;

  // ---- stage v_i and attn rows
  {
    const float4* vg = (const float4*)(v + (size_t)i * RR * D);
    float4* vb = (float4*)vbuf;
    for (int idx = tid; idx < RR * (D / 4); idx += 1024) vb[idx] = vg[idx];
  }
  for (int idx = tid; idx < WW * RR; idx += 1024) {
    int w = idx / RR;
    int r = idx - w * RR;
    att[idx] = attn[(size_t)(c * WW + w) * (BI * RR) + i * RR + r];
  }
  __syncthreads();

  // ---- ctx = attn @ v  -> ybuf   (thread: 5 w-rows x 4 consecutive d)
  {
    const int d4 = nb * 4;
#define CA_DECL(J) float4 ca##J = make_float4(0.f, 0.f, 0.f, 0.f);
    FOR_J5(CA_DECL)
#undef CA_DECL
    for (int r = 0; r < RR; ++r) {
      float4 v4 = *(const float4*)&vbuf[r * D + d4];
#define CA_STEP(J) { float a = att[(wg * 5 + (J)) * RR + r];               \
      ca##J.x = fmaf(a, v4.x, ca##J.x); ca##J.y = fmaf(a, v4.y, ca##J.y);  \
      ca##J.z = fmaf(a, v4.z, ca##J.z); ca##J.w = fmaf(a, v4.w, ca##J.w); }
      FOR_J5(CA_STEP)
#undef CA_STEP
    }
#define CA_STORE(J) *(float4*)&ybuf[(wg * 5 + (J)) * D + d4] = ca##J;
    FOR_J5(CA_STORE)
#undef CA_STORE
  }
  __syncthreads();

  // ---- LN stats per ctx row (16 waves cover 40 rows)
  float* red = att;   // [40][2] : mu, rsigma
  {
    int wid = tid >> 6;
    for (int w = wid; w < WW; w += 16) {
      float s = 0.f, s2 = 0.f;
      #pragma unroll
      for (int dd = 0; dd < D; dd += 64) {
        float x = ybuf[w * D + dd + lane];
        s += x; s2 += x * x;
      }
      #pragma unroll
      for (int off = 32; off; off >>= 1) {
        s  += __shfl_down(s, off);
        s2 += __shfl_down(s2, off);
      }
      if (!lane) {
        float mu  = s * (1.f / D);
        float var = s2 * (1.f / D) - mu * mu;
        red[w * 2]     = mu;
        red[w * 2 + 1] = 1.f / sqrtf(fmaxf(var, 0.f) + 1e-5f);
      }
    }
  }
  __syncthreads();

  // ---- apply LN in place (thread owns column col, half the rows)
  {
    int col  = tid & 511;
    int half = tid >> 9;                 // 0 or 1
    float gg = g4[col], bb = b4[col];
    #pragma unroll
    for (int w = half; w < WW; w += 2) {
      float mu = red[w * 2], rs = red[w * 2 + 1];
      float x = ybuf[w * D + col];
      ybuf[w * D + col] = (x - mu) * rs * gg + bb;
    }
  }

  // ---- out = y @ Wo^T + bo, fused with num/den accumulation
  // thread owns columns n_j = nb + 128*j (j=0..3) for its 5 w-rows
  const float bo0 = bo[nb], bo1 = bo[nb + 128], bo2 = bo[nb + 256],
              bo3 = bo[nb + 384];
#define OA_DECL(J) float4 oa##J = make_float4(bo0, bo1, bo2, bo3);
  FOR_J5(OA_DECL)
#undef OA_DECL
  float4* slab = (float4*)vbuf;   // [8][512] float4 Wo chunk
  for (int ch = 0; ch < 16; ++ch) {
    __syncthreads();              // previous chunk fully consumed
    #pragma unroll
    for (int l = 0; l < 4; ++l) {
      int fi = tid + l * 1024;    // 0..4095 — linear copy
      slab[fi] = Wo4[ch * 4096 + fi];
    }
    __syncthreads();
    #pragma unroll 2
    for (int kbl = 0; kbl < 8; ++kbl) {
      float4 wo0 = slab[kbl * 512 + nb];
      float4 wo1 = slab[kbl * 512 + nb + 128];
      float4 wo2 = slab[kbl * 512 + nb + 256];
      float4 wo3 = slab[kbl * 512 + nb + 384];
      int kk = (ch * 8 + kbl) * 4;
#define OA_STEP(J) {                                                        \
      float4 y4 = *(const float4*)&ybuf[(wg * 5 + (J)) * D + kk];           \
      oa##J.x += y4.x*wo0.x + y4.y*wo0.y + y4.z*wo0.z + y4.w*wo0.w;         \
      oa##J.y += y4.x*wo1.x + y4.y*wo1.y + y4.z*wo1.z + y4.w*wo1.w;         \
      oa##J.z += y4.x*wo2.x + y4.y*wo2.y + y4.z*wo2.z + y4.w*wo2.w;         \
      oa##J.w += y4.x*wo3.x + y4.y*wo3.y + y4.z*wo3.z + y4.w*wo3.w; }
      FOR_J5(OA_STEP)
#undef OA_STEP
    }
  }

  // ---- score: num = out.q, den = ||out||; reduce over n per w
  float* red2 = att + 80;   // [40][2 halves][2]
  const float* qbase = q + (size_t)c * WW * D;
  int h = (tid >> 6) & 1;
#define SC_STEP(J) {                                                        \
    int w = wg * 5 + (J);                                                   \
    const float* qrow = qbase + (size_t)w * D + nb;                         \
    float q0 = qrow[0], q1 = qrow[128], q2 = qrow[256], q3 = qrow[384];     \
    float np = oa##J.x*q0 + oa##J.y*q1 + oa##J.z*q2 + oa##J.w*q3;           \
    float dp = oa##J.x*oa##J.x + oa##J.y*oa##J.y + oa##J.z*oa##J.z          \
             + oa##J.w*oa##J.w;                                             \
    _Pragma("unroll")                                                       \
    for (int off = 32; off; off >>= 1) {                                    \
      np += __shfl_down(np, off);                                           \
      dp += __shfl_down(dp, off);                                           \
    }                                                                       \
    if (!lane) {                                                            \
      red2[(w * 2 + h) * 2]     = np;                                       \
      red2[(w * 2 + h) * 2 + 1] = dp;                                       \
    } }
  FOR_J5(SC_STEP)
#undef SC_STEP
  __syncthreads();
  if (tid < WW) {
    float num = red2[(tid * 2) * 2]     + red2[(tid * 2 + 1) * 2];
    float den = red2[(tid * 2) * 2 + 1] + red2[(tid * 2 + 1) * 2 + 1];
    float s = num / (sqrtf(den) + 1e-8f);
    out[((size_t)i * BC + c) * WW + tid] = (tid < cap_lens[c]) ? s : -1.0f;
  }
}

// ---------------------------------------------------------------------------
extern "C" void kernel_launch(void* const* d_in, const int* in_sizes, int n_in,
                              void* d_out, int out_size, void* d_ws, size_t ws_size,
                              hipStream_t stream)
{
  const float* imgs     = (const float*)d_in[0];
  const float* caps     = (const float*)d_in[1];
  const int*   img_lens = (const int*)d_in[2];
  const int*   cap_lens = (const int*)d_in[3];
  const float* Wq = (const float*)d_in[4];
  const float* bq = (const float*)d_in[5];
  const float* Wk = (const float*)d_in[6];
  const float* bk = (const float*)d_in[7];
  const float* Wv = (const float*)d_in[8];
  const float* bv = (const float*)d_in[9];
  const float* Wo = (const float*)d_in[10];
  const float* bo = (const float*)d_in[11];
  const float* g1 = (const float*)d_in[12];
  const float* b1 = (const float*)d_in[13];
  const float* g2 = (const float*)d_in[14];
  const float* b2 = (const float*)d_in[15];
  const float* g3 = (const float*)d_in[16];
  const float* b3 = (const float*)d_in[17];
  const float* g4 = (const float*)d_in[18];
  const float* b4 = (const float*)d_in[19];
  float* out = (float*)d_out;

  // Workspace layout (floats):
  //   stats_cap 2*2560 | stats_img 2*2304 | qb 2560*512 | kb 2304*512
  //   vb 2304*512 | Sb 2560*2304 | Wo4 512*512
  const size_t WS_FLOATS =
      (size_t)2 * (BC * WW) + 2 * (BI * RR) +
      (size_t)BC * WW * D + 2 * (size_t)BI * RR * D +
      (size_t)BC * WW * BI * RR + (size_t)D * D;
  if (ws_size < WS_FLOATS * sizeof(float)) return;  // guard: fault-free diag

  float*  ws        = (float*)d_ws;
  float2* stats_cap = (float2*)ws;                         // 2560
  float2* stats_img = stats_cap + BC * WW;                 // 2304
  float*  qb  = (float*)(stats_img + BI * RR);             // 2560*512
  float*  kb  = qb + (size_t)BC * WW * D;                  // 2304*512
  float*  vb  = kb + (size_t)BI * RR * D;                  // 2304*512
  float*  Sb  = vb + (size_t)BI * RR * D;                  // 2560*2304
  float*  Wo4 = Sb + (size_t)BC * WW * BI * RR;            // 512*512

  row_stats_k<<<BC * WW, 256, 0, stream>>>(caps, cap_lens, WW, stats_cap);
  row_stats_k<<<BI * RR, 256, 0, stream>>>(imgs, img_lens, RR, stats_img);
  pack_wo_k<<<(D * (D / 4)) / 256, 256, 0, stream>>>((const float4*)Wo, (float4*)Wo4);

  qkv_gemm_k<<<dim3(4, 20, 3), 256, 0, stream>>>(
      imgs, caps, stats_img, stats_cap, img_lens, cap_lens,
      Wq, bq, Wk, bk, Wv, bv, g1, b1, g2, b2, g3, b3, qb, kb, vb);

  s_gemm_k<<<dim3(18, 20), 256, 0, stream>>>(qb, kb, Sb);

  softmax36_k<<<640, 256, 0, stream>>>(Sb, img_lens);

  fused_k<<<dim3(BI, BC), 1024, 0, stream>>>(
      qb, vb, Sb, (const float4*)Wo4, bo, g4, b4, cap_lens, out);
}

// Round 14
// 690.695 us; speedup vs baseline: 19.3179x; 2.6982x over previous
//
#include <hip/hip_runtime.h>
#include <math.h>

#define D   512
#define BI  64
#define RR  36
#define BC  64
#define WW  40

typedef __attribute__((ext_vector_type(8))) _Float16 f16x8;
typedef __attribute__((ext_vector_type(4))) _Float16 f16x4;
typedef __attribute__((ext_vector_type(4))) float    f32x4;

// ---------------------------------------------------------------- row stats
__global__ __launch_bounds__(256) void row_stats_k(
    const float* __restrict__ X, const int* __restrict__ lens,
    int rpb, float2* __restrict__ out)
{
  int row = blockIdx.x;
  int b = row / rpb;
  int pos = row - b * rpb;
  bool valid = pos < lens[b];
  int tid = threadIdx.x;
  float s = 0.f, s2 = 0.f;
  if (valid) {
    float2 v = *(const float2*)(X + (size_t)row * D + tid * 2);
    s = v.x + v.y;
    s2 = v.x * v.x + v.y * v.y;
  }
  #pragma unroll
  for (int off = 32; off; off >>= 1) {
    s  += __shfl_down(s, off);
    s2 += __shfl_down(s2, off);
  }
  __shared__ float red[4][2];
  int wid = tid >> 6, lane = tid & 63;
  if (!lane) { red[wid][0] = s; red[wid][1] = s2; }
  __syncthreads();
  if (!tid) {
    s  = red[0][0] + red[1][0] + red[2][0] + red[3][0];
    s2 = red[0][1] + red[1][1] + red[2][1] + red[3][1];
    float mu  = s * (1.f / D);
    float var = s2 * (1.f / D) - mu * mu;
    out[row] = make_float2(mu, 1.f / sqrtf(fmaxf(var, 0.f) + 1e-5f));
  }
}

// ------------------------------------------------- pack Wo -> fp16 row-major
__global__ __launch_bounds__(256) void pack_wo_h(
    const float4* __restrict__ Wo, f16x4* __restrict__ whf)
{
  int idx = blockIdx.x * 256 + threadIdx.x;   // 0..65535
  float4 x = Wo[idx];
  f16x4 h;
  h.x = (_Float16)x.x; h.y = (_Float16)x.y;
  h.z = (_Float16)x.z; h.w = (_Float16)x.w;
  whf[idx] = h;
}

// ---------------------------------------------------------------- GEMM body
struct GemmP {
  const float* A; const float* Bm; float* C;
  int M, N, ldc; float alpha;
  const float* bias;
  const float2* stats; const float* g; const float* b;
  const int* lens; int rpb;
};

__device__ __forceinline__ void gemm_body(GemmP p, int bx, int by)
{
  __shared__ float As[16][132];
  __shared__ float Bs[16][132];
  int m0 = by * 128, n0 = bx * 128;
  int tid = threadIdx.x;
  int tm = tid & 15, tn = tid >> 4;
  float acc[8][8] = {{0.f}};
  for (int k0 = 0; k0 < D; k0 += 16) {
    #pragma unroll
    for (int l = 0; l < 2; ++l) {
      int fi  = tid + l * 256;        // 0..511
      int row = fi >> 2;              // 0..127
      int kq  = (fi & 3) << 2;        // 0,4,8,12
      {
        int gm = m0 + row;
        float4 x = *(const float4*)(p.A + (size_t)gm * D + k0 + kq);
        if (p.stats) {
          int bb = gm / p.rpb;
          bool val = (gm - bb * p.rpb) < p.lens[bb];
          float2 st = p.stats[gm];
          float4 gg  = *(const float4*)(p.g + k0 + kq);
          float4 bbv = *(const float4*)(p.b + k0 + kq);
          x.x = ((val ? x.x : 0.f) - st.x) * st.y * gg.x + bbv.x;
          x.y = ((val ? x.y : 0.f) - st.x) * st.y * gg.y + bbv.y;
          x.z = ((val ? x.z : 0.f) - st.x) * st.y * gg.z + bbv.z;
          x.w = ((val ? x.w : 0.f) - st.x) * st.y * gg.w + bbv.w;
        }
        As[kq + 0][row] = x.x; As[kq + 1][row] = x.y;
        As[kq + 2][row] = x.z; As[kq + 3][row] = x.w;
      }
      {
        float4 y = *(const float4*)(p.Bm + (size_t)(n0 + row) * D + k0 + kq);
        Bs[kq + 0][row] = y.x; Bs[kq + 1][row] = y.y;
        Bs[kq + 2][row] = y.z; Bs[kq + 3][row] = y.w;
      }
    }
    __syncthreads();
    #pragma unroll
    for (int kk = 0; kk < 16; ++kk) {
      float a[8], bb[8];
      *(float4*)(a)      = *(const float4*)&As[kk][tm * 8];
      *(float4*)(a + 4)  = *(const float4*)&As[kk][tm * 8 + 4];
      *(float4*)(bb)     = *(const float4*)&Bs[kk][tn * 8];
      *(float4*)(bb + 4) = *(const float4*)&Bs[kk][tn * 8 + 4];
      #pragma unroll
      for (int ii = 0; ii < 8; ++ii)
        #pragma unroll
        for (int jj = 0; jj < 8; ++jj)
          acc[ii][jj] = fmaf(a[ii], bb[jj], acc[ii][jj]);
    }
    __syncthreads();
  }
  #pragma unroll
  for (int ii = 0; ii < 8; ++ii) {
    int gm = m0 + tm * 8 + ii;
    #pragma unroll
    for (int jj = 0; jj < 8; jj += 4) {
      int gn = n0 + tn * 8 + jj;
      float4 o;
      o.x = acc[ii][jj+0] * p.alpha + (p.bias ? p.bias[gn+0] : 0.f);
      o.y = acc[ii][jj+1] * p.alpha + (p.bias ? p.bias[gn+1] : 0.f);
      o.z = acc[ii][jj+2] * p.alpha + (p.bias ? p.bias[gn+2] : 0.f);
      o.w = acc[ii][jj+3] * p.alpha + (p.bias ? p.bias[gn+3] : 0.f);
      *(float4*)(p.C + (size_t)gm * p.ldc + gn) = o;
    }
  }
}

// q/k/v projections: grid.z selects which projection.
__global__ __launch_bounds__(256) void qkv_gemm_k(
    const float* imgs, const float* caps,
    const float2* stats_img, const float2* stats_cap,
    const int* img_lens, const int* cap_lens,
    const float* Wq, const float* bq, const float* Wk, const float* bk,
    const float* Wv, const float* bv,
    const float* g1, const float* b1, const float* g2, const float* b2,
    const float* g3, const float* b3,
    float* qo, float* ko, float* vo)
{
  GemmP p;
  p.N = D; p.ldc = D; p.alpha = 1.f;
  int z = blockIdx.z;
  if (z == 0) {
    p.A = caps; p.stats = stats_cap; p.g = g1; p.b = b1;
    p.lens = cap_lens; p.rpb = WW;
    p.Bm = Wq; p.bias = bq; p.C = qo; p.M = BC * WW;
  } else if (z == 1) {
    p.A = imgs; p.stats = stats_img; p.g = g2; p.b = b2;
    p.lens = img_lens; p.rpb = RR;
    p.Bm = Wk; p.bias = bk; p.C = ko; p.M = BI * RR;
  } else {
    p.A = imgs; p.stats = stats_img; p.g = g3; p.b = b3;
    p.lens = img_lens; p.rpb = RR;
    p.Bm = Wv; p.bias = bv; p.C = vo; p.M = BI * RR;
  }
  if (blockIdx.y * 128 >= p.M) return;
  gemm_body(p, blockIdx.x, blockIdx.y);
}

// sims GEMM: S[cw][ir] = (1/sqrt(512)) * q[cw] . k[ir]
__global__ __launch_bounds__(256) void s_gemm_k(
    const float* q, const float* k, float* S)
{
  GemmP p;
  p.A = q; p.Bm = k; p.C = S;
  p.M = BC * WW; p.N = BI * RR; p.ldc = BI * RR;
  p.alpha = 0.04419417382415922f;   // 1/sqrt(512)
  p.bias = nullptr; p.stats = nullptr; p.g = nullptr; p.b = nullptr;
  p.lens = nullptr; p.rpb = 1;
  gemm_body(p, blockIdx.x, blockIdx.y);
}

// ------------------------------------------------------- masked row softmax
__global__ __launch_bounds__(256) void softmax36_k(
    float* __restrict__ S, const int* __restrict__ img_lens)
{
  int row = blockIdx.x * 256 + threadIdx.x;    // 0..163839 = (c*W+w)*64 + i
  int cw = row >> 6, i = row & 63;
  float* p = S + (size_t)cw * (BI * RR) + i * RR;
  int len = img_lens[i];
  float sv[RR];
  float m = -1e30f;
  #pragma unroll
  for (int r = 0; r < RR; ++r) {
    sv[r] = p[r];
    if (r < len && sv[r] > m) m = sv[r];
  }
  float sum = 0.f;
  #pragma unroll
  for (int r = 0; r < RR; ++r) {
    float e = (r < len) ? __expf(sv[r] - m) : 0.f;
    sv[r] = e; sum += e;
  }
  float inv = 1.f / sum;
  #pragma unroll
  for (int r = 0; r < RR; ++r) p[r] = sv[r] * inv;
}

// ------------------- fused: ctx = attn@v, LN, out = y@Wo^T+bo, cosine score
//
// R12 WIN anchored: waves_per_eu(4,4) kills the spill (WRITE 23GB->640KB,
// 14.3ms->1.9ms). Now VALU/LDS-bound (VALUBusy 69%, MfmaUtil 0). This round:
// move the 86-GFLOP out-GEMM to mfma_f32_16x16x32_f16. fp16 (not bf16) for
// absmax safety: y is LN-normalized O(1), Wo is O(0.04) -> rel err ~7e-4.
// Only y/Wo rounded; ctx/acc/bias/score stay fp32.
// Fragments (m89/m91/m97-verified layouts): lane l:
//   A[m=l&15][k=8*(l>>4)+j]  B[n=l&15][k=8*(l>>4)+j]  (both row-major [outer][K])
//   D[row=4*(l>>4)+r][col=l&15]
// yh[48][512] fp16 (pad rows zeroed) and woh[512][64] fp16 are XOR-swizzled
// (byte ^= (row&7)<<4) to kill the row-major power-of-2-stride bank conflict.
#define FOR_J5(X) X(0) X(1) X(2) X(3) X(4)

__global__ __launch_bounds__(1024)
__attribute__((amdgpu_waves_per_eu(4, 4)))
void fused_k(
    const float* __restrict__ q, const float* __restrict__ v,
    const float* __restrict__ attn, const _Float16* __restrict__ whf,
    const float* __restrict__ bo, const float* __restrict__ g4,
    const float* __restrict__ b4, const int* __restrict__ cap_lens,
    float* __restrict__ out)
{
  __shared__ float sm[(WW + RR) * D + WW * RR];   // 161408 B
  float* ybuf = sm;                     // 40*512 f32 (ctx)      -> woh fp16
  float* vbuf = sm + WW * D;            // 36*512 f32 (v)        -> yh  fp16
  float* att  = sm + (WW + RR) * D;     // 1440 f32 (attn -> red @0 / red2 @128)
  _Float16* yh  = (_Float16*)vbuf;      // [48][512] fp16 swizzled (48 KB)
  _Float16* woh = (_Float16*)ybuf;      // [512][64] fp16 swizzled chunk (64 KB)
  const int i = blockIdx.x, c = blockIdx.y;
  const int tid = threadIdx.x;
  const int nb = tid & 127;             // ctx: column block 0..127
  const int wg = tid >> 7;              // ctx: row group 0..7 (5 rows each)
  const int lane = tid & 63;

  // ---- stage v_i and attn rows
  {
    const float4* vg = (const float4*)(v + (size_t)i * RR * D);
    float4* vb = (float4*)vbuf;
    for (int idx = tid; idx < RR * (D / 4); idx += 1024) vb[idx] = vg[idx];
  }
  for (int idx = tid; idx < WW * RR; idx += 1024) {
    int w = idx / RR;
    int r = idx - w * RR;
    att[idx] = attn[(size_t)(c * WW + w) * (BI * RR) + i * RR + r];
  }
  __syncthreads();

  // ---- ctx = attn @ v  -> ybuf fp32  (thread: 5 w-rows x 4 consecutive d)
  {
    const int d4 = nb * 4;
#define CA_DECL(J) float4 ca##J = make_float4(0.f, 0.f, 0.f, 0.f);
    FOR_J5(CA_DECL)
#undef CA_DECL
    for (int r = 0; r < RR; ++r) {
      float4 v4 = *(const float4*)&vbuf[r * D + d4];
#define CA_STEP(J) { float a = att[(wg * 5 + (J)) * RR + r];               \
      ca##J.x = fmaf(a, v4.x, ca##J.x); ca##J.y = fmaf(a, v4.y, ca##J.y);  \
      ca##J.z = fmaf(a, v4.z, ca##J.z); ca##J.w = fmaf(a, v4.w, ca##J.w); }
      FOR_J5(CA_STEP)
#undef CA_STEP
    }
#define CA_STORE(J) *(float4*)&ybuf[(wg * 5 + (J)) * D + d4] = ca##J;
    FOR_J5(CA_STORE)
#undef CA_STORE
  }
  __syncthreads();

  // ---- LN stats per ctx row (16 waves cover 40 rows)
  float* red = att;   // [40][2] : mu, rsigma
  {
    int wid = tid >> 6;
    for (int w = wid; w < WW; w += 16) {
      float s = 0.f, s2 = 0.f;
      #pragma unroll
      for (int dd = 0; dd < D; dd += 64) {
        float x = ybuf[w * D + dd + lane];
        s += x; s2 += x * x;
      }
      #pragma unroll
      for (int off = 32; off; off >>= 1) {
        s  += __shfl_down(s, off);
        s2 += __shfl_down(s2, off);
      }
      if (!lane) {
        float mu  = s * (1.f / D);
        float var = s2 * (1.f / D) - mu * mu;
        red[w * 2]     = mu;
        red[w * 2 + 1] = 1.f / sqrtf(fmaxf(var, 0.f) + 1e-5f);
      }
    }
  }
  __syncthreads();

  // ---- apply LN: ybuf fp32 -> yh fp16 (swizzled); zero pad rows 40..47
  {
    int col  = tid & 511;
    int half = tid >> 9;                 // 0 or 1
    float gg = g4[col], bb = b4[col];
    for (int w = half; w < WW; w += 2) {
      float mu = red[w * 2], rs = red[w * 2 + 1];
      float x = (ybuf[w * D + col] - mu) * rs * gg + bb;
      int byte = w * 1024 + ((col * 2) ^ ((w & 7) << 4));
      *(_Float16*)((char*)yh + byte) = (_Float16)x;
    }
    for (int w = WW + half; w < 48; w += 2) {
      int byte = w * 1024 + ((col * 2) ^ ((w & 7) << 4));
      *(_Float16*)((char*)yh + byte) = (_Float16)0.f;
    }
  }
  // (no barrier here: ch-loop top barrier covers yh writes & ybuf death)

  // ---- out = yh @ Wo^T via MFMA; acc in fp32 fragments
  const int wv  = tid >> 6;             // wave 0..15
  const int l15 = lane & 15, lhi = lane >> 4;
  const int swz = (l15 & 7) << 4;       // row&7 == l15&7 for all our rows
  f32x4 acc0 = {0.f,0.f,0.f,0.f}, acc1 = {0.f,0.f,0.f,0.f};
  f32x4 acc2 = {0.f,0.f,0.f,0.f}, acc3 = {0.f,0.f,0.f,0.f};
  f32x4 acc4 = {0.f,0.f,0.f,0.f}, acc5 = {0.f,0.f,0.f,0.f};
  const int nt0 = wv * 2;               // this wave's two N-tiles
  const int nRow0 = nt0 * 16 + l15, nRow1 = nRow0 + 16;

  for (int ch = 0; ch < 8; ++ch) {      // K chunks of 64
    __syncthreads();                    // woh region free (prev consumed)
    #pragma unroll
    for (int t = 0; t < 4; ++t) {       // stage Wo chunk [512 n][64 k] fp16
      int idx = tid + t * 1024;         // 0..4095
      int n = idx >> 3, kb = idx & 7;
      f16x8 vwo = *(const f16x8*)(whf + (size_t)n * 512 + ch * 64 + kb * 8);
      int byte = n * 128 + ((kb * 16) ^ ((n & 7) << 4));
      *(f16x8*)((char*)woh + byte) = vwo;
    }
    __syncthreads();
    #pragma unroll
    for (int ks = 0; ks < 2; ++ks) {    // two K=32 MFMA steps per chunk
      int kgb = (ch * 64 + ks * 32 + 8 * lhi) * 2;   // byte col in yh row
      int klb = (ks * 32 + 8 * lhi) * 2;             // byte col in woh row
      f16x8 A0 = *(f16x8*)((char*)yh + (l15     ) * 1024 + (kgb ^ swz));
      f16x8 A1 = *(f16x8*)((char*)yh + (l15 + 16) * 1024 + (kgb ^ swz));
      f16x8 A2 = *(f16x8*)((char*)yh + (l15 + 32) * 1024 + (kgb ^ swz));
      f16x8 B0 = *(f16x8*)((char*)woh + nRow0 * 128 + (klb ^ swz));
      f16x8 B1 = *(f16x8*)((char*)woh + nRow1 * 128 + (klb ^ swz));
      acc0 = __builtin_amdgcn_mfma_f32_16x16x32_f16(A0, B0, acc0, 0, 0, 0);
      acc1 = __builtin_amdgcn_mfma_f32_16x16x32_f16(A0, B1, acc1, 0, 0, 0);
      acc2 = __builtin_amdgcn_mfma_f32_16x16x32_f16(A1, B0, acc2, 0, 0, 0);
      acc3 = __builtin_amdgcn_mfma_f32_16x16x32_f16(A1, B1, acc3, 0, 0, 0);
      acc4 = __builtin_amdgcn_mfma_f32_16x16x32_f16(A2, B0, acc4, 0, 0, 0);
      acc5 = __builtin_amdgcn_mfma_f32_16x16x32_f16(A2, B1, acc5, 0, 0, 0);
    }
  }

  // ---- bias + cosine score from fragments
  float* red2 = att + 128;              // [16 waves][40 rows][2]
  const float* qbase = q + (size_t)c * WW * D;
  {
    const int col0 = nt0 * 16 + l15, col1 = col0 + 16;
    const float bo0v = bo[col0], bo1v = bo[col1];
#define SCORE_R(AV0, AV1, ROW) {                                            \
    float o0 = (AV0) + bo0v, o1 = (AV1) + bo1v;                             \
    float np = 0.f;                                                         \
    float dp = o0 * o0 + o1 * o1;                                           \
    if ((ROW) < WW) {                                                       \
      const float* qr = qbase + (size_t)(ROW) * D;                          \
      np = o0 * qr[col0] + o1 * qr[col1];                                   \
    }                                                                       \
    np += __shfl_xor(np, 1);  dp += __shfl_xor(dp, 1);                      \
    np += __shfl_xor(np, 2);  dp += __shfl_xor(dp, 2);                      \
    np += __shfl_xor(np, 4);  dp += __shfl_xor(dp, 4);                      \
    np += __shfl_xor(np, 8);  dp += __shfl_xor(dp, 8);                      \
    if (l15 == 0 && (ROW) < WW) {                                           \
      red2[(wv * 40 + (ROW)) * 2]     = np;                                 \
      red2[(wv * 40 + (ROW)) * 2 + 1] = dp;                                 \
    } }
    int rb0 = 4 * lhi;
    SCORE_R(acc0.x, acc1.x, rb0 + 0)  SCORE_R(acc0.y, acc1.y, rb0 + 1)
    SCORE_R(acc0.z, acc1.z, rb0 + 2)  SCORE_R(acc0.w, acc1.w, rb0 + 3)
    int rb1 = 16 + 4 * lhi;
    SCORE_R(acc2.x, acc3.x, rb1 + 0)  SCORE_R(acc2.y, acc3.y, rb1 + 1)
    SCORE_R(acc2.z, acc3.z, rb1 + 2)  SCORE_R(acc2.w, acc3.w, rb1 + 3)
    int rb2 = 32 + 4 * lhi;
    SCORE_R(acc4.x, acc5.x, rb2 + 0)  SCORE_R(acc4.y, acc5.y, rb2 + 1)
    SCORE_R(acc4.z, acc5.z, rb2 + 2)  SCORE_R(acc4.w, acc5.w, rb2 + 3)
#undef SCORE_R
  }
  __syncthreads();
  if (tid < WW) {
    float num = 0.f, den = 0.f;
    #pragma unroll
    for (int w2 = 0; w2 < 16; ++w2) {
      num += red2[(w2 * 40 + tid) * 2];
      den += red2[(w2 * 40 + tid) * 2 + 1];
    }
    float s = num / (sqrtf(den) + 1e-8f);
    out[((size_t)i * BC + c) * WW + tid] = (tid < cap_lens[c]) ? s : -1.0f;
  }
}

// ---------------------------------------------------------------------------
extern "C" void kernel_launch(void* const* d_in, const int* in_sizes, int n_in,
                              void* d_out, int out_size, void* d_ws, size_t ws_size,
                              hipStream_t stream)
{
  const float* imgs     = (const float*)d_in[0];
  const float* caps     = (const float*)d_in[1];
  const int*   img_lens = (const int*)d_in[2];
  const int*   cap_lens = (const int*)d_in[3];
  const float* Wq = (const float*)d_in[4];
  const float* bq = (const float*)d_in[5];
  const float* Wk = (const float*)d_in[6];
  const float* bk = (const float*)d_in[7];
  const float* Wv = (const float*)d_in[8];
  const float* bv = (const float*)d_in[9];
  const float* Wo = (const float*)d_in[10];
  const float* bo = (const float*)d_in[11];
  const float* g1 = (const float*)d_in[12];
  const float* b1 = (const float*)d_in[13];
  const float* g2 = (const float*)d_in[14];
  const float* b2 = (const float*)d_in[15];
  const float* g3 = (const float*)d_in[16];
  const float* b3 = (const float*)d_in[17];
  const float* g4 = (const float*)d_in[18];
  const float* b4 = (const float*)d_in[19];
  float* out = (float*)d_out;

  // Workspace layout (floats):
  //   stats_cap 2*2560 | stats_img 2*2304 | qb 2560*512 | kb 2304*512
  //   vb 2304*512 | Sb 2560*2304 | whf 512*512 fp16 (fits old D*D f32 slot)
  const size_t WS_FLOATS =
      (size_t)2 * (BC * WW) + 2 * (BI * RR) +
      (size_t)BC * WW * D + 2 * (size_t)BI * RR * D +
      (size_t)BC * WW * BI * RR + (size_t)D * D;
  if (ws_size < WS_FLOATS * sizeof(float)) return;  // guard: fault-free diag

  float*  ws        = (float*)d_ws;
  float2* stats_cap = (float2*)ws;                         // 2560
  float2* stats_img = stats_cap + BC * WW;                 // 2304
  float*  qb  = (float*)(stats_img + BI * RR);             // 2560*512
  float*  kb  = qb + (size_t)BC * WW * D;                  // 2304*512
  float*  vb  = kb + (size_t)BI * RR * D;                  // 2304*512
  float*  Sb  = vb + (size_t)BI * RR * D;                  // 2560*2304
  _Float16* whf = (_Float16*)(Sb + (size_t)BC * WW * BI * RR); // 512*512 fp16

  row_stats_k<<<BC * WW, 256, 0, stream>>>(caps, cap_lens, WW, stats_cap);
  row_stats_k<<<BI * RR, 256, 0, stream>>>(imgs, img_lens, RR, stats_img);
  pack_wo_h<<<256, 256, 0, stream>>>((const float4*)Wo, (f16x4*)whf);

  qkv_gemm_k<<<dim3(4, 20, 3), 256, 0, stream>>>(
      imgs, caps, stats_img, stats_cap, img_lens, cap_lens,
      Wq, bq, Wk, bk, Wv, bv, g1, b1, g2, b2, g3, b3, qb, kb, vb);

  s_gemm_k<<<dim3(18, 20), 256, 0, stream>>>(qb, kb, Sb);

  softmax36_k<<<640, 256, 0, stream>>>(Sb, img_lens);

  fused_k<<<dim3(BI, BC), 1024, 0, stream>>>(
      qb, vb, Sb, whf, bo, g4, b4, cap_lens, out);
}